// Round 7
// baseline (5447.570 us; speedup 1.0000x reference)
//
#include <hip/hip_runtime.h>
#include <math.h>

#define Bb     32
#define NVv    400
#define Mm     512
#define Kk     32
#define Nn     501
#define MAXIT  10
#define EPSd   1e-12f
#define NT     256

typedef float v2f __attribute__((ext_vector_type(2)));

// DPP add-combine: x += dpp_perm(x). Lanes outside rmask add old=0 (no-op).
#define DPP_ADD(x, ctrl, rmask)                                                        \
    (x) += __int_as_float(__builtin_amdgcn_update_dpp(                                 \
              0, __float_as_int(x), (ctrl), (rmask), 0xF, false))

#define QUAD_PERM_X1 0xB1   // xor-1
#define QUAD_PERM_X2 0x4E   // xor-2
#define ROW_HALF_MIR 0x141  // xor-4 (quads uniform)
#define ROW_MIR      0x140  // xor-8 (8-groups uniform)
#define ROW_BCAST15  0x142  // row r+1 += row r lane15
#define ROW_BCAST31  0x143  // rows 2,3 += lane31

// 16-lane (DPP row) sum: every lane of the row ends with the row total
#define REDUCE16(x)                 \
    DPP_ADD(x, QUAD_PERM_X1, 0xF);  \
    DPP_ADD(x, QUAD_PERM_X2, 0xF);  \
    DPP_ADD(x, ROW_HALF_MIR, 0xF);  \
    DPP_ADD(x, ROW_MIR,      0xF)

// One coordinate-descent step, wave 0 only, barrier-free.
// SC: current s-row slice (consumed). SP: refilled by prefetch for in1.
// VO0/VO1: vold octet (consumed). VN0/VN1: refilled (V[in1]).
// SNI: current Snrms (consumed). SNN: refilled (Snrms[in1]).
#define STEP(SC, SP, VO0, VO1, VN0, VN1, SNI, SNN)                                  \
  {                                                                                 \
    /* prefetch for in1: s row (global), V octet + snrm + perm (LDS) */             \
    const float* srow_ = S + (size_t)in1 * Mm + c4;                                 \
    SP[0] = *(const float4*)(srow_ +  0);                                           \
    SP[1] = *(const float4*)(srow_ +  4);                                           \
    SP[2] = *(const float4*)(srow_ +  8);                                           \
    SP[3] = *(const float4*)(srow_ + 12);                                           \
    SP[4] = *(const float4*)(srow_ + 16);                                           \
    SP[5] = *(const float4*)(srow_ + 20);                                           \
    SP[6] = *(const float4*)(srow_ + 24);                                           \
    SP[7] = *(const float4*)(srow_ + 28);                                           \
    VN0 = *(const float4*)&V_lds[in1 * Kk + kb];                                    \
    VN1 = *(const float4*)&V_lds[in1 * Kk + kb + 4];                                \
    SNN = sn_lds[in1];                                                              \
    const int in2_ = permc[sip];                                                    \
    sip = (sip + 1 == cnt) ? 0 : (sip + 1);                                         \
    /* gemv: p[j] = sum over my 32 m's of W[kb+j][m]*s[m] (packed f32) */           \
    v2f sc2[16];                                                                    \
    _Pragma("unroll")                                                               \
    for (int q_ = 0; q_ < 8; ++q_) {                                                \
        sc2[2*q_]   = (v2f){SC[q_].x, SC[q_].y};                                    \
        sc2[2*q_+1] = (v2f){SC[q_].z, SC[q_].w};                                    \
    }                                                                               \
    float p_[8];                                                                    \
    _Pragma("unroll")                                                               \
    for (int j_ = 0; j_ < 8; ++j_) {                                                \
        v2f a_ = w2[j_][0] * sc2[0];                                                \
        v2f b_ = w2[j_][1] * sc2[1];                                                \
        _Pragma("unroll")                                                           \
        for (int q_ = 2; q_ < 16; q_ += 2) {                                        \
            a_ += w2[j_][q_]     * sc2[q_];                                         \
            b_ += w2[j_][q_ + 1] * sc2[q_ + 1];                                     \
        }                                                                           \
        a_ += b_;                                                                   \
        p_[j_] = a_.x + a_.y;                                                       \
    }                                                                               \
    _Pragma("unroll")                                                               \
    for (int j_ = 0; j_ < 8; ++j_) { REDUCE16(p_[j_]); }                            \
    const float g0_ = fmaf(-SNI, VO0.x, p_[0]);                                     \
    const float g1_ = fmaf(-SNI, VO0.y, p_[1]);                                     \
    const float g2_ = fmaf(-SNI, VO0.z, p_[2]);                                     \
    const float g3_ = fmaf(-SNI, VO0.w, p_[3]);                                     \
    const float g4_ = fmaf(-SNI, VO1.x, p_[4]);                                     \
    const float g5_ = fmaf(-SNI, VO1.y, p_[5]);                                     \
    const float g6_ = fmaf(-SNI, VO1.z, p_[6]);                                     \
    const float g7_ = fmaf(-SNI, VO1.w, p_[7]);                                     \
    float qn_ = ((g0_*g0_ + g1_*g1_) + (g2_*g2_ + g3_*g3_))                         \
              + ((g4_*g4_ + g5_*g5_) + (g6_*g6_ + g7_*g7_));                        \
    DPP_ADD(qn_, ROW_BCAST15, 0xA);                                                 \
    DPP_ADD(qn_, ROW_BCAST31, 0xC);                                                 \
    const float gn2_ = __int_as_float(                                              \
        __builtin_amdgcn_readlane(__float_as_int(qn_), 63));                        \
    const float rden_ = -1.0f / fmaxf(sqrtf(gn2_), EPSd);                           \
    float4 vna_, vnb_;                                                              \
    vna_.x = g0_*rden_; vna_.y = g1_*rden_; vna_.z = g2_*rden_; vna_.w = g3_*rden_; \
    vnb_.x = g4_*rden_; vnb_.y = g5_*rden_; vnb_.z = g6_*rden_; vnb_.w = g7_*rden_; \
    if (c == 0) {  /* one lane per row writes the row's k-octet */                  \
        *(float4*)&V_lds[i * Kk + kb]     = vna_;                                   \
        *(float4*)&V_lds[i * Kk + kb + 4] = vnb_;                                   \
    }                                                                               \
    const float dv_[8] = { vna_.x - VO0.x, vna_.y - VO0.y,                          \
                           vna_.z - VO0.z, vna_.w - VO0.w,                          \
                           vnb_.x - VO1.x, vnb_.y - VO1.y,                          \
                           vnb_.z - VO1.z, vnb_.w - VO1.w };                        \
    _Pragma("unroll")                                                               \
    for (int j_ = 0; j_ < 8; ++j_) {                                                \
        v2f db_ = (v2f){dv_[j_], dv_[j_]};                                          \
        _Pragma("unroll")                                                           \
        for (int q_ = 0; q_ < 16; ++q_) w2[j_][q_] += db_ * sc2[q_];                \
    }                                                                               \
    if (cnt == 1) { VN0 = vna_; VN1 = vnb_; }  /* prefetched V[i] was stale */      \
    i = in1; in1 = in2_;                                                            \
  }

__global__ void __launch_bounds__(NT, 1)
satnet_kernel(const float* __restrict__ S, const float* __restrict__ z,
              const int* __restrict__ isin, const float* __restrict__ Vinit,
              const int* __restrict__ perm, float* __restrict__ out)
{
    __shared__ __align__(16) float V_lds[Nn * Kk];   // 64128 B
    __shared__ __align__(16) float W_lds[Kk * Mm];   // 65536 B (staging: phase3 -> wave0 regs)
    __shared__ float z_lds[Nn];
    __shared__ int   inp_lds[Nn];
    __shared__ float sn_lds[Nn];
    __shared__ int   permc[Nn - 1];
    __shared__ float v0_lds[Kk];
    __shared__ int   cnt_lds;

    const int b    = blockIdx.x;
    const int t    = threadIdx.x;
    const int lane = t & 63;
    const int w    = t >> 6;            // 4 waves
    const float PI_F = 3.14159274101257324f;

    // wave-0 main-loop lane geometry: row g owns k-octet, col c owns 32 m's
    const int g  = lane >> 4;           // 0..3
    const int c  = lane & 15;           // 0..15
    const int kb = g << 3;              // k base (8g)
    const int c4 = c << 5;              // m base (32c)

    // ---------- phase 0: z_full / inp / Snrms ----------
    for (int r = t; r < Nn; r += NT) {
        float zv; int iv;
        if (r == 0)        { zv = 1.f;                iv = 1; }
        else if (r <= NVv) { zv = z[b * NVv + r - 1]; iv = isin[b * NVv + r - 1]; }
        else               { zv = 0.f;                iv = 0; }
        z_lds[r]   = zv;
        inp_lds[r] = (iv > 0) ? 1 : 0;

        const float4* row = (const float4*)(S + (size_t)r * Mm);
        float a0 = 0.f, a1 = 0.f, a2 = 0.f, a3 = 0.f;
        #pragma unroll 4
        for (int j = 0; j < Mm / 4; ++j) {
            float4 v = row[j];
            a0 += v.x * v.x; a1 += v.y * v.y; a2 += v.z * v.z; a3 += v.w * v.w;
        }
        sn_lds[r] = (a0 + a1) + (a2 + a3);
    }
    __syncthreads();

    // ---------- phase 1: V normalize + pin ----------
    {
        const int r   = t >> 5;   // 0..7
        const int kk2 = t & 31;   // k

        if (t < 32) {  // row 0 -> v0
            float v = Vinit[((size_t)b * Nn) * Kk + t];
            float q = v * v;
            q += __shfl_xor(q, 1, 32); q += __shfl_xor(q, 2, 32);
            q += __shfl_xor(q, 4, 32); q += __shfl_xor(q, 8, 32);
            q += __shfl_xor(q, 16, 32);
            float nv = v / fmaxf(sqrtf(q), EPSd);
            v0_lds[t] = nv;
            V_lds[t] = nv;
        }
        __syncthreads();
        float v0k = v0_lds[kk2];

        for (int it = 0; it < 63; ++it) {
            int n = 1 + it * 8 + r;
            if (n <= 500) {
                float v = Vinit[((size_t)b * Nn + n) * Kk + kk2];
                float q = v * v;
                q += __shfl_xor(q, 1, 32); q += __shfl_xor(q, 2, 32);
                q += __shfl_xor(q, 4, 32); q += __shfl_xor(q, 8, 32);
                q += __shfl_xor(q, 16, 32);
                float nv = v / fmaxf(sqrtf(q), EPSd);
                float res = nv;
                if (inp_lds[n]) {  // uniform per 32-lane group
                    float d = nv * v0k;
                    d += __shfl_xor(d, 1, 32); d += __shfl_xor(d, 2, 32);
                    d += __shfl_xor(d, 4, 32); d += __shfl_xor(d, 8, 32);
                    d += __shfl_xor(d, 16, 32);
                    float vp = nv - d * v0k;
                    float q2 = vp * vp;
                    q2 += __shfl_xor(q2, 1, 32); q2 += __shfl_xor(q2, 2, 32);
                    q2 += __shfl_xor(q2, 4, 32); q2 += __shfl_xor(q2, 8, 32);
                    q2 += __shfl_xor(q2, 16, 32);
                    vp = vp / fmaxf(sqrtf(q2), EPSd);
                    float ang = PI_F * z_lds[n];
                    res = -cosf(ang) * v0k + sinf(ang) * vp;
                }
                V_lds[n * Kk + kk2] = res;
            }
        }
    }
    __syncthreads();

    // ---------- phase 2 (wave 0): compact perm (pinned coords are exact no-ops) ----------
    if (w == 0) {
        int cc = 0;
        for (int base = 0; base < Nn - 1; base += 64) {
            int idx = base + lane;
            int iv = 0; bool keep = false;
            if (idx < Nn - 1) { iv = perm[idx]; keep = (inp_lds[iv] == 0); }
            unsigned long long mk = __ballot(keep);
            int pos = cc + (int)__popcll(mk & ((1ull << lane) - 1ull));
            if (keep) permc[pos] = iv;
            cc += (int)__popcll(mk);
        }
        if (lane == 0) cnt_lds = cc;
    }

    // ---------- phase 3 (all 4 waves, concurrent with phase 2): W -> W_lds ----------
    // thread owns k in [8kg,8kg+8) x m in [8cm,8cm+8)
    {
        const int kg  = t >> 6;        // 0..3
        const int cm  = t & 63;        // 0..63
        const int kb3 = kg << 3;
        const int mb3 = cm << 3;
        v2f wv[8][4];
        #pragma unroll
        for (int j = 0; j < 8; ++j) {
            #pragma unroll
            for (int q = 0; q < 4; ++q) wv[j][q] = (v2f){0.f, 0.f};
        }
        #pragma unroll 4
        for (int n = 0; n < Nn; ++n) {
            float4 va = *(const float4*)&V_lds[n * Kk + kb3];
            float4 vb = *(const float4*)&V_lds[n * Kk + kb3 + 4];
            float4 s0 = *(const float4*)&S[(size_t)n * Mm + mb3];
            float4 s1 = *(const float4*)&S[(size_t)n * Mm + mb3 + 4];
            v2f sm[4] = { {s0.x, s0.y}, {s0.z, s0.w}, {s1.x, s1.y}, {s1.z, s1.w} };
            float vk[8] = {va.x, va.y, va.z, va.w, vb.x, vb.y, vb.z, vb.w};
            #pragma unroll
            for (int j = 0; j < 8; ++j) {
                v2f vv = (v2f){vk[j], vk[j]};
                #pragma unroll
                for (int q = 0; q < 4; ++q) wv[j][q] += vv * sm[q];
            }
        }
        #pragma unroll
        for (int j = 0; j < 8; ++j) {
            *(float4*)&W_lds[(kb3 + j) * Mm + mb3] =
                make_float4(wv[j][0].x, wv[j][0].y, wv[j][1].x, wv[j][1].y);
            *(float4*)&W_lds[(kb3 + j) * Mm + mb3 + 4] =
                make_float4(wv[j][2].x, wv[j][2].y, wv[j][3].x, wv[j][3].y);
        }
    }
    __syncthreads();
    const int cnt = cnt_lds;

    // ---------- main loop: wave 0 only, zero barriers ----------
    if (w == 0 && cnt > 0) {
        // load W fragment: w2[j][q] = W[kb+j][c4 + 2q, c4 + 2q + 1]
        v2f w2[8][16];
        #pragma unroll
        for (int j = 0; j < 8; ++j) {
            #pragma unroll
            for (int qq = 0; qq < 8; ++qq) {
                float4 x = *(const float4*)&W_lds[(kb + j) * Mm + c4 + 4 * qq];
                w2[j][2*qq]   = (v2f){x.x, x.y};
                w2[j][2*qq+1] = (v2f){x.z, x.w};
            }
        }

        int i   = permc[0];
        int in1 = (cnt > 1) ? permc[1] : i;
        int sip = (cnt > 2) ? 2 : 0;   // == 2 % cnt

        float4 sX[8], sY[8];
        const float* srow0 = S + (size_t)i * Mm + c4;
        #pragma unroll
        for (int qq = 0; qq < 8; ++qq) sX[qq] = *(const float4*)(srow0 + 4 * qq);
        float4 vX0 = *(const float4*)&V_lds[i * Kk + kb];
        float4 vX1 = *(const float4*)&V_lds[i * Kk + kb + 4];
        float4 vY0, vY1;
        float  snX = sn_lds[i], snY;

        const int total = MAXIT * cnt;
        const int pairs = total >> 1;
        #pragma unroll 1
        for (int it2 = 0; it2 < pairs; ++it2) {
            STEP(sX, sY, vX0, vX1, vY0, vY1, snX, snY)
            STEP(sY, sX, vY0, vY1, vX0, vX1, snY, snX)
        }
        if (total & 1) {
            STEP(sX, sY, vX0, vX1, vY0, vY1, snX, snY)
        }
    }
    __syncthreads();

    // ---------- final: z_out = arccos(clip(-V.v0))/pi ----------
    {
        const int r   = t >> 5;   // 0..7
        const int kk2 = t & 31;
        float v0k = v0_lds[kk2];
        const float c1 = (float)(1.0 - 1e-7);
        #pragma unroll 1
        for (int it = 0; it < 50; ++it) {
            int n = 1 + it * 8 + r;   // 1..400
            float d = V_lds[n * Kk + kk2] * v0k;
            d += __shfl_xor(d, 1, 32); d += __shfl_xor(d, 2, 32);
            d += __shfl_xor(d, 4, 32); d += __shfl_xor(d, 8, 32);
            d += __shfl_xor(d, 16, 32);
            if (kk2 == 0) {
                float x = -d;
                x = fminf(fmaxf(x, -c1), c1);
                float zo = acosf(x) / PI_F;
                if (inp_lds[n]) zo = z_lds[n];
                out[b * NVv + (n - 1)] = zo;
            }
        }
    }
}

extern "C" void kernel_launch(void* const* d_in, const int* in_sizes, int n_in,
                              void* d_out, int out_size, void* d_ws, size_t ws_size,
                              hipStream_t stream) {
    const float* S     = (const float*)d_in[0];
    const float* z     = (const float*)d_in[1];
    const int*   isin  = (const int*)d_in[2];
    const float* Vinit = (const float*)d_in[3];
    const int*   perm  = (const int*)d_in[4];
    float* outp = (float*)d_out;
    hipLaunchKernelGGL(satnet_kernel, dim3(Bb), dim3(NT), 0, stream,
                       S, z, isin, Vinit, perm, outp);
}